// Round 4
// baseline (248.931 us; speedup 1.0000x reference)
//
#include <hip/hip_runtime.h>
#include <math.h>

#define BSZ 8
#define DDIM 512
#define NND 2048
#define EE 8
#define LLH 64
#define NEDGE 524288
#define BNN 16384          // BSZ*NND
#define ETOT 540672        // NEDGE + BNN
#define OCC 1536           // 3*EE*LLH
#define DQ 16384           // NND*EE (per-third d dimension)

__device__ inline void atomicMaxF(float* addr, float v) {
    if (v >= 0.f) atomicMax((int*)addr, __float_as_int(v));
    else atomicMin((unsigned int*)addr, (unsigned int)__float_as_int(v));
}

// ---- 1. skeleton = latent @ W_dense + b_dense -> [8, 2048] ----
__global__ __launch_bounds__(256) void k_dense(const float* __restrict__ latent,
                                               const float* __restrict__ Wd,
                                               const float* __restrict__ bd,
                                               float* __restrict__ sk) {
    __shared__ float lat[BSZ * DDIM];   // 16 KB
    int tid = threadIdx.x;
    for (int i = tid; i < BSZ * DDIM; i += 256) lat[i] = latent[i];
    __syncthreads();
    int n = blockIdx.x * 32 + (tid & 31);
    int b = tid >> 5;
    float acc = 0.f;
    for (int d = 0; d < DDIM; ++d) acc += lat[b * DDIM + d] * Wd[d * NND + n];
    sk[b * NND + n] = acc + bd[n];
}

// ---- 2. conv1d(K=3, Cin=1, Cout=8, SAME) -> x [16384, 8] ----
__global__ void k_conv1(const float* __restrict__ sk, const float* __restrict__ w1,
                        const float* __restrict__ b1, float* __restrict__ xb) {
    int bn = blockIdx.x * 256 + threadIdx.x;
    if (bn >= BNN) return;
    int n = bn & (NND - 1);
    float sm = (n > 0) ? sk[bn - 1] : 0.f;
    float s0 = sk[bn];
    float sp = (n < NND - 1) ? sk[bn + 1] : 0.f;
    #pragma unroll
    for (int e = 0; e < EE; ++e)
        xb[bn * EE + e] = sm * w1[e] + s0 * w1[EE + e] + sp * w1[2 * EE + e] + b1[e];
}

// ---- 3. GAT Q/K/V projections + per-call init of reduction buffers ----
__global__ void k_gatqkv(const float* __restrict__ xb,
                         const float* __restrict__ Wq, const float* __restrict__ bq,
                         const float* __restrict__ Wk, const float* __restrict__ bk,
                         const float* __restrict__ Wv, const float* __restrict__ gbias,
                         float* __restrict__ Qg, float* __restrict__ Kg,
                         float* __restrict__ Vg, float* __restrict__ hg,
                         float* __restrict__ smax, float* __restrict__ ssum,
                         float* __restrict__ Sb) {
    int i = blockIdx.x * 256 + threadIdx.x;
    if (i >= BNN) return;
    float xr[EE];
    #pragma unroll
    for (int c = 0; c < EE; ++c) xr[c] = xb[i * EE + c];
    #pragma unroll
    for (int j = 0; j < EE; ++j) {
        float q = bq[j], k = bk[j], v = 0.f;
        #pragma unroll
        for (int c = 0; c < EE; ++c) {
            q += xr[c] * Wq[c * EE + j];
            k += xr[c] * Wk[c * EE + j];
            v += xr[c] * Wv[c * EE + j];
        }
        Qg[i * EE + j] = (q >= 0.f) ? q : 0.2f * q;
        Kg[i * EE + j] = (k >= 0.f) ? k : 0.2f * k;
        Vg[i * EE + j] = v;
        hg[i * EE + j] = gbias[j];   // aggregate lands on top of bias
    }
    smax[i] = -INFINITY;
    ssum[i] = 0.f;
    Sb[2 * i] = 0.f;
    Sb[2 * i + 1] = 0.f;
}

// ---- 4. edge scores + segment max ----
__global__ void k_escore(const int* __restrict__ ei, const float* __restrict__ Qg,
                         const float* __restrict__ Kg, float* __restrict__ sc,
                         float* __restrict__ smax) {
    int e = blockIdx.x * 256 + threadIdx.x;
    if (e >= ETOT) return;
    int r, c;
    if (e < NEDGE) { r = ei[e]; c = ei[NEDGE + e]; } else { r = c = e - NEDGE; }
    const float4* Q4 = (const float4*)(Qg + r * EE);
    const float4* K4 = (const float4*)(Kg + c * EE);
    float4 qa = Q4[0], qb2 = Q4[1], ka = K4[0], kb2 = K4[1];
    float s = qa.x * ka.x + qa.y * ka.y + qa.z * ka.z + qa.w * ka.w
            + qb2.x * kb2.x + qb2.y * kb2.y + qb2.z * kb2.z + qb2.w * kb2.w;
    sc[e] = s;
    atomicMaxF(smax + r, s);
}

// ---- 5. exp + segment sum ----
__global__ void k_eexp(const int* __restrict__ ei, const float* __restrict__ smax,
                       float* __restrict__ sc, float* __restrict__ ssum) {
    int e = blockIdx.x * 256 + threadIdx.x;
    if (e >= ETOT) return;
    int r = (e < NEDGE) ? ei[e] : e - NEDGE;
    float ex = __expf(sc[e] - smax[r]);
    sc[e] = ex;
    atomicAdd(ssum + r, ex);
}

// ---- 6. alpha * V scatter-aggregate ----
__global__ void k_eaggr(const int* __restrict__ ei, const float* __restrict__ sc,
                        const float* __restrict__ ssum, const float* __restrict__ Vg,
                        float* __restrict__ hg) {
    long long t = (long long)blockIdx.x * 256 + threadIdx.x;
    if (t >= (long long)ETOT * EE) return;
    int e = (int)(t >> 3), j = (int)(t & 7);
    int r, c;
    if (e < NEDGE) { r = ei[e]; c = ei[NEDGE + e]; } else { r = c = e - NEDGE; }
    float alpha = sc[e] / ssum[r];
    atomicAdd(hg + r * EE + j, alpha * Vg[c * EE + j]);
}

// ---- 7. fused qkv-conv (q,k thirds) + S partial GEMM ----
// grid (128 f-chunks, 8 b), block 256.  F[b][l][f] for f-chunk computed into
// LDS tiles (XOR-swizzled float4 columns), then S[t][s] += sum_f q*k.
__global__ __launch_bounds__(256) void k_convS(const float* __restrict__ hg,
                                               const float* __restrict__ qw,
                                               const float* __restrict__ qb,
                                               float* __restrict__ Sb) {
    int ch = blockIdx.x, b = blockIdx.y;
    int d0 = ch * 128;
    __shared__ float qt[64][132];
    __shared__ float kt[64][132];
    int tid = threadIdx.x;
    int fg = tid & 31, lg = tid >> 5;
    #pragma unroll
    for (int T = 0; T < 2; ++T) {
        int f_full = (T ? 2 * DQ : 0) + d0 + fg * 4;
        int n = f_full / 24;
        int c0 = f_full - n * 24;            // 4-aligned, group never crosses node
        float hv[24];
        #pragma unroll
        for (int r = 0; r < 3; ++r) {
            int nr = n - 1 + r;
            if (nr >= 0 && nr < NND) {
                const float4* hp = (const float4*)(hg + ((size_t)b * NND + nr) * EE);
                float4 h0 = hp[0], h1 = hp[1];
                hv[r*8+0]=h0.x; hv[r*8+1]=h0.y; hv[r*8+2]=h0.z; hv[r*8+3]=h0.w;
                hv[r*8+4]=h1.x; hv[r*8+5]=h1.y; hv[r*8+6]=h1.z; hv[r*8+7]=h1.w;
            } else {
                #pragma unroll
                for (int e = 0; e < 8; ++e) hv[r*8+e] = 0.f;
            }
        }
        float* tile = T ? &kt[0][0] : &qt[0][0];
        #pragma unroll
        for (int ll = 0; ll < 8; ++ll) {
            int l = lg * 8 + ll;
            int o0 = l * 24 + c0;
            float4 acc = *(const float4*)(qb + o0);
            #pragma unroll
            for (int kk = 0; kk < 24; ++kk) {
                float4 w = *(const float4*)(qw + kk * OCC + o0);
                acc.x += hv[kk] * w.x;
                acc.y += hv[kk] * w.y;
                acc.z += hv[kk] * w.z;
                acc.w += hv[kk] * w.w;
            }
            int pc = fg ^ ((l >> 2) & 7);    // XOR swizzle on float4 column
            *(float4*)(tile + l * 132 + pc * 4) = acc;
        }
    }
    __syncthreads();
    int tq = tid >> 4, sq = tid & 15;
    float acc[4][4] = {};
    for (int fb4 = 0; fb4 < 32; ++fb4) {
        float4 q4[4], k4[4];
        #pragma unroll
        for (int u = 0; u < 4; ++u) {
            q4[u] = *(const float4*)(&qt[tq * 4 + u][(fb4 ^ (tq & 7)) * 4]);
            k4[u] = *(const float4*)(&kt[sq * 4 + u][(fb4 ^ (sq & 7)) * 4]);
        }
        #pragma unroll
        for (int u = 0; u < 4; ++u)
            #pragma unroll
            for (int w = 0; w < 4; ++w)
                acc[u][w] += q4[u].x * k4[w].x + q4[u].y * k4[w].y
                           + q4[u].z * k4[w].z + q4[u].w * k4[w].w;
    }
    float* S = Sb + (size_t)b * LLH * LLH;
    #pragma unroll
    for (int u = 0; u < 4; ++u)
        #pragma unroll
        for (int w = 0; w < 4; ++w)
            atomicAdd(S + (tq * 4 + u) * LLH + sq * 4 + w, acc[u][w]);
}

// ---- 8. row softmax over S -> atT[b][s][t] ----
__global__ void k_softmax(const float* __restrict__ Sb, float* __restrict__ atT) {
    int b = blockIdx.x >> 6, t = blockIdx.x & 63;
    int s = threadIdx.x;
    float v = Sb[((size_t)b * LLH + t) * LLH + s];
    float m = v;
    #pragma unroll
    for (int off = 32; off > 0; off >>= 1) m = fmaxf(m, __shfl_xor(m, off));
    float e = __expf(v - m);
    float sum = e;
    #pragma unroll
    for (int off = 32; off > 0; off >>= 1) sum += __shfl_xor(sum, off);
    atT[((size_t)b * LLH + s) * LLH + t] = e / sum;
}

// ---- 9. fused v-conv + attnV -> out[b][t][d] ----
// grid (128 f-chunks, 8 b), block 256.
__global__ __launch_bounds__(256) void k_convAV(const float* __restrict__ hg,
                                                const float* __restrict__ qw,
                                                const float* __restrict__ qb,
                                                const float* __restrict__ atT,
                                                float* __restrict__ out) {
    int ch = blockIdx.x, b = blockIdx.y;
    int d0 = ch * 128;
    __shared__ float vt[64][132];
    __shared__ float at[64][68];
    int tid = threadIdx.x;
    {   // stage attn^T [s][t]
        const float4* src = (const float4*)(atT + (size_t)b * LLH * LLH);
        #pragma unroll
        for (int r = 0; r < 4; ++r) {
            int idx = r * 256 + tid;
            int s = idx >> 4, t4 = idx & 15;
            *(float4*)(&at[s][t4 * 4]) = src[idx];
        }
    }
    int fg = tid & 31, lg = tid >> 5;
    int f_full = DQ + d0 + fg * 4;
    int n = f_full / 24;
    int c0 = f_full - n * 24;
    float hv[24];
    #pragma unroll
    for (int r = 0; r < 3; ++r) {
        int nr = n - 1 + r;
        if (nr >= 0 && nr < NND) {
            const float4* hp = (const float4*)(hg + ((size_t)b * NND + nr) * EE);
            float4 h0 = hp[0], h1 = hp[1];
            hv[r*8+0]=h0.x; hv[r*8+1]=h0.y; hv[r*8+2]=h0.z; hv[r*8+3]=h0.w;
            hv[r*8+4]=h1.x; hv[r*8+5]=h1.y; hv[r*8+6]=h1.z; hv[r*8+7]=h1.w;
        } else {
            #pragma unroll
            for (int e = 0; e < 8; ++e) hv[r*8+e] = 0.f;
        }
    }
    #pragma unroll
    for (int ll = 0; ll < 8; ++ll) {
        int s = lg * 8 + ll;
        int o0 = s * 24 + c0;
        float4 acc = *(const float4*)(qb + o0);
        #pragma unroll
        for (int kk = 0; kk < 24; ++kk) {
            float4 w = *(const float4*)(qw + kk * OCC + o0);
            acc.x += hv[kk] * w.x;
            acc.y += hv[kk] * w.y;
            acc.z += hv[kk] * w.z;
            acc.w += hv[kk] * w.w;
        }
        int pc = fg ^ ((s >> 2) & 7);
        *(float4*)(&vt[s][pc * 4]) = acc;
    }
    __syncthreads();
    int t0 = (tid & 15) * 4, dg = tid >> 4;   // t0: 4 rows, dg: 8 d-columns
    float a0[8] = {}, a1[8] = {}, a2[8] = {}, a3[8] = {};
    for (int s = 0; s < 64; ++s) {
        float4 a4 = *(const float4*)(&at[s][t0]);
        int g = (s >> 2) & 7;
        float4 v0 = *(const float4*)(&vt[s][((dg * 2) ^ g) * 4]);
        float4 v1 = *(const float4*)(&vt[s][((dg * 2 + 1) ^ g) * 4]);
        a0[0] += a4.x*v0.x; a0[1] += a4.x*v0.y; a0[2] += a4.x*v0.z; a0[3] += a4.x*v0.w;
        a0[4] += a4.x*v1.x; a0[5] += a4.x*v1.y; a0[6] += a4.x*v1.z; a0[7] += a4.x*v1.w;
        a1[0] += a4.y*v0.x; a1[1] += a4.y*v0.y; a1[2] += a4.y*v0.z; a1[3] += a4.y*v0.w;
        a1[4] += a4.y*v1.x; a1[5] += a4.y*v1.y; a1[6] += a4.y*v1.z; a1[7] += a4.y*v1.w;
        a2[0] += a4.z*v0.x; a2[1] += a4.z*v0.y; a2[2] += a4.z*v0.z; a2[3] += a4.z*v0.w;
        a2[4] += a4.z*v1.x; a2[5] += a4.z*v1.y; a2[6] += a4.z*v1.z; a2[7] += a4.z*v1.w;
        a3[0] += a4.w*v0.x; a3[1] += a4.w*v0.y; a3[2] += a4.w*v0.z; a3[3] += a4.w*v0.w;
        a3[4] += a4.w*v1.x; a3[5] += a4.w*v1.y; a3[6] += a4.w*v1.z; a3[7] += a4.w*v1.w;
    }
    float* ob = out + ((size_t)b * LLH + t0) * DQ + d0 + dg * 8;
    *(float4*)(ob)              = make_float4(a0[0], a0[1], a0[2], a0[3]);
    *(float4*)(ob + 4)          = make_float4(a0[4], a0[5], a0[6], a0[7]);
    *(float4*)(ob + DQ)         = make_float4(a1[0], a1[1], a1[2], a1[3]);
    *(float4*)(ob + DQ + 4)     = make_float4(a1[4], a1[5], a1[6], a1[7]);
    *(float4*)(ob + 2 * DQ)     = make_float4(a2[0], a2[1], a2[2], a2[3]);
    *(float4*)(ob + 2 * DQ + 4) = make_float4(a2[4], a2[5], a2[6], a2[7]);
    *(float4*)(ob + 3 * DQ)     = make_float4(a3[0], a3[1], a3[2], a3[3]);
    *(float4*)(ob + 3 * DQ + 4) = make_float4(a3[4], a3[5], a3[6], a3[7]);
}

extern "C" void kernel_launch(void* const* d_in, const int* in_sizes, int n_in,
                              void* d_out, int out_size, void* d_ws, size_t ws_size,
                              hipStream_t stream) {
    (void)in_sizes; (void)n_in; (void)out_size; (void)ws_size;
    const float* latent = (const float*)d_in[0];
    const int*   ei     = (const int*)d_in[1];
    const float* Wd     = (const float*)d_in[2];
    const float* bd     = (const float*)d_in[3];
    const float* w1     = (const float*)d_in[4];
    const float* b1     = (const float*)d_in[5];
    const float* Wq     = (const float*)d_in[6];
    const float* bq     = (const float*)d_in[7];
    const float* Wk     = (const float*)d_in[8];
    const float* bk     = (const float*)d_in[9];
    const float* Wv     = (const float*)d_in[10];
    const float* gbias  = (const float*)d_in[11];
    const float* qw     = (const float*)d_in[12];
    const float* qb     = (const float*)d_in[13];
    float* out = (float*)d_out;

    float* ws   = (float*)d_ws;
    float* sk   = ws;                        // 16384
    float* xb   = sk + BNN;                  // 131072
    float* Qg   = xb + BNN * EE;             // 131072
    float* Kg   = Qg + BNN * EE;             // 131072
    float* Vg   = Kg + BNN * EE;             // 131072
    float* hg   = Vg + BNN * EE;             // 131072
    float* smax = hg + BNN * EE;             // 16384
    float* ssum = smax + BNN;                // 16384
    float* sc   = ssum + BNN;                // 540672
    float* Sb   = sc + ETOT;                 // 32768
    float* atT  = Sb + BSZ * LLH * LLH;      // 32768
    // total ~1.3M floats (~5.2 MB) -> L2/L3 resident

    k_dense<<<dim3(64), dim3(256), 0, stream>>>(latent, Wd, bd, sk);
    k_conv1<<<dim3(64), dim3(256), 0, stream>>>(sk, w1, b1, xb);
    k_gatqkv<<<dim3(64), dim3(256), 0, stream>>>(xb, Wq, bq, Wk, bk, Wv, gbias,
                                                 Qg, Kg, Vg, hg, smax, ssum, Sb);
    k_escore<<<dim3(ETOT / 256), dim3(256), 0, stream>>>(ei, Qg, Kg, sc, smax);
    k_eexp<<<dim3(ETOT / 256), dim3(256), 0, stream>>>(ei, smax, sc, ssum);
    k_eaggr<<<dim3(ETOT * EE / 256), dim3(256), 0, stream>>>(ei, sc, ssum, Vg, hg);
    k_convS<<<dim3(128, 8), dim3(256), 0, stream>>>(hg, qw, qb, Sb);
    k_softmax<<<dim3(512), dim3(64), 0, stream>>>(Sb, atT);
    k_convAV<<<dim3(128, 8), dim3(256), 0, stream>>>(hg, qw, qb, atT, out);
}